// Round 1
// baseline (121.295 us; speedup 1.0000x reference)
//
#include <hip/hip_runtime.h>
#include <hip/hip_bf16.h>
#include <stdint.h>

#define NB 8
#define NT 2048
#define NC 1024
#define NH 64

typedef __attribute__((ext_vector_type(8))) short bf16x8;
typedef __attribute__((ext_vector_type(4))) float f32x4;

#define MFMA(a, b, c) __builtin_amdgcn_mfma_f32_16x16x32_bf16((a), (b), (c), 0, 0, 0)

static __device__ __forceinline__ short f2bf(float f) {
  union { float f; uint32_t u; } v; v.f = f;
  uint32_t r = v.u + 0x7FFFu + ((v.u >> 16) & 1u);  // RNE bf16
  return (short)(r >> 16);
}

// ---------------------------------------------------------------------------
// Kernel 0: build Wt[192][1024] bf16 = concat(Wq^T * 0.125, Wk^T, Wv^T)
// (softmax scale 1/sqrt(64)=0.125 folded into Wq)
// ---------------------------------------------------------------------------
__global__ __launch_bounds__(256) void w_prep(const float* __restrict__ Wq,
                                              const float* __restrict__ Wk,
                                              const float* __restrict__ Wv,
                                              short* __restrict__ Wt) {
  __shared__ short tile[64][68];
  const int blk = blockIdx.x;          // 48 blocks: 3 mats x 16 k-tiles
  const int mat = blk / 16;
  const int k0 = (blk % 16) * 64;
  const float* W = (mat == 0) ? Wq : (mat == 1) ? Wk : Wv;
  const float scale = (mat == 0) ? 0.125f : 1.0f;
  const int tid = threadIdx.x;
  {
    int kk = tid >> 2;                 // 0..63 (k within tile)
    int h0 = (tid & 3) * 16;           // 0,16,32,48
    const float* src = W + (size_t)(k0 + kk) * NH + h0;
#pragma unroll
    for (int i = 0; i < 16; ++i) tile[kk][h0 + i] = f2bf(src[i] * scale);
  }
  __syncthreads();
  {
    int j = tid >> 2;                  // output row = head col 0..63
    int kk0 = (tid & 3) * 16;
    bf16x8 t0, t1;
#pragma unroll
    for (int i = 0; i < 8; ++i) { t0[i] = tile[kk0 + i][j]; t1[i] = tile[kk0 + 8 + i][j]; }
    short* dst = Wt + (size_t)(mat * 64 + j) * NC + k0 + kk0;
    *(bf16x8*)dst = t0;
    *(bf16x8*)(dst + 8) = t1;
  }
}

// ---------------------------------------------------------------------------
// Kernel 1: QKV projection. Tile 64 rows x 192 cols, K-step 32.
// x fp32 -> bf16 on the fly; Wt already bf16 transposed.
// ---------------------------------------------------------------------------
__global__ __launch_bounds__(256) void qkv_proj(const float* __restrict__ x,
                                                const short* __restrict__ Wt,
                                                short* __restrict__ Qo,
                                                short* __restrict__ Ko,
                                                short* __restrict__ Vo) {
  __shared__ short xs[64][40];     // +8 pad: row stride 80B -> conflict-free-ish
  __shared__ short wt[192][40];
  const int tid = threadIdx.x;
  const int lane = tid & 63;
  const int wave = tid >> 6;
  const int l15 = lane & 15;
  const int hi = lane >> 4;
  const int kgrp = hi * 8;
  const int m0 = blockIdx.x * 64;

  f32x4 acc[12];
#pragma unroll
  for (int f = 0; f < 12; ++f) acc[f] = (f32x4){0.f, 0.f, 0.f, 0.f};

  for (int k0 = 0; k0 < NC; k0 += 32) {
    __syncthreads();
    {   // stage x tile 64x32 (fp32 -> bf16)
      int r = tid >> 2, c0 = (tid & 3) * 8;
      const float* src = x + (size_t)(m0 + r) * NC + k0 + c0;
      float4 a = *(const float4*)src;
      float4 b = *(const float4*)(src + 4);
      short* d = &xs[r][c0];
      d[0] = f2bf(a.x); d[1] = f2bf(a.y); d[2] = f2bf(a.z); d[3] = f2bf(a.w);
      d[4] = f2bf(b.x); d[5] = f2bf(b.y); d[6] = f2bf(b.z); d[7] = f2bf(b.w);
    }
    {   // stage Wt tile 192x32 (already bf16) : 768 chunks of 8 shorts
#pragma unroll
      for (int c = tid; c < 768; c += 256) {
        int j = c >> 2, kk0 = (c & 3) * 8;
        *(bf16x8*)&wt[j][kk0] = *(const bf16x8*)(Wt + (size_t)j * NC + k0 + kk0);
      }
    }
    __syncthreads();
    bf16x8 a = *(const bf16x8*)&xs[wave * 16 + l15][kgrp];
#pragma unroll
    for (int f = 0; f < 12; ++f) {
      bf16x8 b = *(const bf16x8*)&wt[f * 16 + l15][kgrp];
      acc[f] = MFMA(a, b, acc[f]);
    }
  }
  // epilogue: C/D layout col=lane&15, row=(lane>>4)*4+reg
#pragma unroll
  for (int f = 0; f < 12; ++f) {
    short* dst = (f < 4) ? Qo : (f < 8) ? Ko : Vo;
    int h = (f & 3) * 16 + l15;
#pragma unroll
    for (int r = 0; r < 4; ++r) {
      int t = m0 + wave * 16 + hi * 4 + r;
      dst[(size_t)t * NH + h] = f2bf(acc[f][r]);
    }
  }
}

// ---------------------------------------------------------------------------
// Kernel 2: flash attention, causal. One block per (batch, 64-row q-tile).
// 4 waves; wave w owns q-rows [w*16, w*16+16). Q in regs; K, V^T in LDS.
// ---------------------------------------------------------------------------
__global__ __launch_bounds__(256) void attn(const short* __restrict__ Q,
                                            const short* __restrict__ K,
                                            const short* __restrict__ V,
                                            float* __restrict__ out) {
  __shared__ short Ks[64][72];         // K tile  [key][h]
  __shared__ short Vt[64][72];         // V tile transposed [h][key]
  __shared__ short Ps[4][16][72];      // per-wave P (16 q-rows x 64 keys)
  const int tid = threadIdx.x;
  const int lane = tid & 63;
  const int wave = tid >> 6;
  const int l15 = lane & 15;
  const int hi = lane >> 4;
  const int kgrp = hi * 8;
  const int b = blockIdx.x >> 5;       // 8 batches
  const int qt = blockIdx.x & 31;      // 32 q-tiles of 64 rows

  const size_t qoff = ((size_t)b * NT + qt * 64) * NH;
  const int qrow = wave * 16 + l15;
  const bf16x8 qf0 = *(const bf16x8*)(Q + qoff + (size_t)qrow * NH + kgrp);
  const bf16x8 qf1 = *(const bf16x8*)(Q + qoff + (size_t)qrow * NH + 32 + kgrp);

  f32x4 oacc[4];
#pragma unroll
  for (int f = 0; f < 4; ++f) oacc[f] = (f32x4){0.f, 0.f, 0.f, 0.f};
  float m_[4], l_[4];
#pragma unroll
  for (int r = 0; r < 4; ++r) { m_[r] = -INFINITY; l_[r] = 0.f; }

  for (int kt = 0; kt <= qt; ++kt) {
    __syncthreads();                   // protect prior-iter LDS reads
    {   // stage K tile and V^T tile: thread -> row=tid>>2, 16 cols
      int r = tid >> 2, c0 = (tid & 3) * 16;
      const size_t base = ((size_t)b * NT + kt * 64 + r) * NH + c0;
      bf16x8 k0 = *(const bf16x8*)(K + base);
      bf16x8 k1 = *(const bf16x8*)(K + base + 8);
      *(bf16x8*)&Ks[r][c0] = k0;
      *(bf16x8*)&Ks[r][c0 + 8] = k1;
      bf16x8 v0 = *(const bf16x8*)(V + base);
      bf16x8 v1 = *(const bf16x8*)(V + base + 8);
#pragma unroll
      for (int i = 0; i < 8; ++i) Vt[c0 + i][r] = v0[i];
#pragma unroll
      for (int i = 0; i < 8; ++i) Vt[c0 + 8 + i][r] = v1[i];
    }
    __syncthreads();

    // S = Q K^T  (16 rows x 64 keys per wave): 4 col-frags x 2 k-steps
    f32x4 s[4];
#pragma unroll
    for (int f = 0; f < 4; ++f) {
      s[f] = (f32x4){0.f, 0.f, 0.f, 0.f};
      bf16x8 b0 = *(const bf16x8*)&Ks[f * 16 + l15][kgrp];
      bf16x8 b1 = *(const bf16x8*)&Ks[f * 16 + l15][32 + kgrp];
      s[f] = MFMA(qf0, b0, s[f]);
      s[f] = MFMA(qf1, b1, s[f]);
    }
    if (kt == qt) {                    // causal mask on the diagonal tile
#pragma unroll
      for (int f = 0; f < 4; ++f)
#pragma unroll
        for (int r = 0; r < 4; ++r)
          if (f * 16 + l15 > wave * 16 + hi * 4 + r) s[f][r] = -INFINITY;
    }
    // online softmax: row r lives at (hi*4+r), cols spread over l15 lanes
    float mt[4];
#pragma unroll
    for (int r = 0; r < 4; ++r)
      mt[r] = fmaxf(fmaxf(s[0][r], s[1][r]), fmaxf(s[2][r], s[3][r]));
#pragma unroll
    for (int d = 1; d < 16; d <<= 1)
#pragma unroll
      for (int r = 0; r < 4; ++r) mt[r] = fmaxf(mt[r], __shfl_xor(mt[r], d));
    float alpha[4], rs[4];
#pragma unroll
    for (int r = 0; r < 4; ++r) {
      float mn = fmaxf(m_[r], mt[r]);
      alpha[r] = __expf(m_[r] - mn);
      m_[r] = mn;
      rs[r] = 0.f;
    }
#pragma unroll
    for (int f = 0; f < 4; ++f)
#pragma unroll
      for (int r = 0; r < 4; ++r) {
        float p = __expf(s[f][r] - m_[r]);
        s[f][r] = p;
        rs[r] += p;
      }
#pragma unroll
    for (int d = 1; d < 16; d <<= 1)
#pragma unroll
      for (int r = 0; r < 4; ++r) rs[r] += __shfl_xor(rs[r], d);
#pragma unroll
    for (int r = 0; r < 4; ++r) l_[r] = l_[r] * alpha[r] + rs[r];
#pragma unroll
    for (int f = 0; f < 4; ++f)
#pragma unroll
      for (int r = 0; r < 4; ++r) oacc[f][r] *= alpha[r];

    // P -> LDS (transpose to A-fragment layout), then PV
#pragma unroll
    for (int f = 0; f < 4; ++f)
#pragma unroll
      for (int r = 0; r < 4; ++r)
        Ps[wave][hi * 4 + r][f * 16 + l15] = f2bf(s[f][r]);

    bf16x8 pa0 = *(const bf16x8*)&Ps[wave][l15][kgrp];
    bf16x8 pa1 = *(const bf16x8*)&Ps[wave][l15][32 + kgrp];
#pragma unroll
    for (int f = 0; f < 4; ++f) {
      bf16x8 vb0 = *(const bf16x8*)&Vt[f * 16 + l15][kgrp];
      bf16x8 vb1 = *(const bf16x8*)&Vt[f * 16 + l15][32 + kgrp];
      oacc[f] = MFMA(pa0, vb0, oacc[f]);
      oacc[f] = MFMA(pa1, vb1, oacc[f]);
    }
  }
  // epilogue: out fp32 [b][t][h]
#pragma unroll
  for (int f = 0; f < 4; ++f)
#pragma unroll
    for (int r = 0; r < 4; ++r) {
      int t = qt * 64 + wave * 16 + hi * 4 + r;
      out[((size_t)b * NT + t) * NH + f * 16 + l15] = oacc[f][r] / l_[r];
    }
}

// ---------------------------------------------------------------------------
extern "C" void kernel_launch(void* const* d_in, const int* in_sizes, int n_in,
                              void* d_out, int out_size, void* d_ws, size_t ws_size,
                              hipStream_t stream) {
  const float* x  = (const float*)d_in[0];
  const float* Wq = (const float*)d_in[1];
  const float* Wk = (const float*)d_in[2];
  const float* Wv = (const float*)d_in[3];
  float* out = (float*)d_out;

  char* ws = (char*)d_ws;
  short* Wt = (short*)ws;                          // 192*1024*2 = 384 KB
  short* Qb = (short*)(ws + (size_t)(1 << 20));    // 2 MB each
  short* Kb = (short*)(ws + (size_t)(3 << 20));
  short* Vb = (short*)(ws + (size_t)(5 << 20));

  hipLaunchKernelGGL(w_prep, dim3(48), dim3(256), 0, stream, Wq, Wk, Wv, Wt);
  hipLaunchKernelGGL(qkv_proj, dim3(256), dim3(256), 0, stream, x, Wt, Qb, Kb, Vb);
  hipLaunchKernelGGL(attn, dim3(8 * 32), dim3(256), 0, stream, Qb, Kb, Vb, out);
}

// Round 2
// 76.933 us; speedup vs baseline: 1.5766x; 1.5766x over previous
//
#include <hip/hip_runtime.h>
#include <hip/hip_bf16.h>
#include <stdint.h>

#define NB 8
#define NT 2048
#define NC 1024
#define NH 64

typedef __attribute__((ext_vector_type(8))) short bf16x8;
typedef __attribute__((ext_vector_type(4))) float f32x4;

#define MFMA(a, b, c) __builtin_amdgcn_mfma_f32_16x16x32_bf16((a), (b), (c), 0, 0, 0)

static __device__ __forceinline__ short f2bf(float f) {
  union { float f; uint32_t u; } v; v.f = f;
  uint32_t r = v.u + 0x7FFFu + ((v.u >> 16) & 1u);  // RNE bf16
  return (short)(r >> 16);
}
static __device__ __forceinline__ float bf2f(short h) {
  union { uint32_t u; float f; } v; v.u = ((uint32_t)(uint16_t)h) << 16;
  return v.f;
}
static __device__ __forceinline__ void gload_lds16(const void* g, void* l) {
  __builtin_amdgcn_global_load_lds(
      (const __attribute__((address_space(1))) uint32_t*)g,
      (__attribute__((address_space(3))) uint32_t*)l, 16, 0, 0);
}

// ---------------------------------------------------------------------------
// Kernel 0: build Wt[192][1024] bf16 = concat(Wq^T * 0.125, Wk^T, Wv^T)
// ---------------------------------------------------------------------------
__global__ __launch_bounds__(256) void w_prep(const float* __restrict__ Wq,
                                              const float* __restrict__ Wk,
                                              const float* __restrict__ Wv,
                                              short* __restrict__ Wt) {
  __shared__ short tile[64][68];
  const int blk = blockIdx.x;          // 48 blocks: 3 mats x 16 k-tiles
  const int mat = blk / 16;
  const int k0 = (blk % 16) * 64;
  const float* W = (mat == 0) ? Wq : (mat == 1) ? Wk : Wv;
  const float scale = (mat == 0) ? 0.125f : 1.0f;
  const int tid = threadIdx.x;
  {
    int kk = tid >> 2;
    int h0 = (tid & 3) * 16;
    const float* src = W + (size_t)(k0 + kk) * NH + h0;
#pragma unroll
    for (int i = 0; i < 16; ++i) tile[kk][h0 + i] = f2bf(src[i] * scale);
  }
  __syncthreads();
  {
    int j = tid >> 2;
    int kk0 = (tid & 3) * 16;
    bf16x8 t0, t1;
#pragma unroll
    for (int i = 0; i < 8; ++i) { t0[i] = tile[kk0 + i][j]; t1[i] = tile[kk0 + 8 + i][j]; }
    short* dst = Wt + (size_t)(mat * 64 + j) * NC + k0 + kk0;
    *(bf16x8*)dst = t0;
    *(bf16x8*)(dst + 8) = t1;
  }
}

// ---------------------------------------------------------------------------
// Kernel 1: QKV projection v2. 512 blocks x 32 rows, K-step 64.
// global_load_lds (width 16) for x(fp32) and Wt(bf16), XOR-swizzled source.
// LDS: xs 32x64 fp32 (8KB, swz bits4-6 ^= bits8-10)
//      wt 192x64 bf16 (24KB, swz bits4-6 ^= bits7-9)
// ---------------------------------------------------------------------------
__global__ __launch_bounds__(256) void qkv_proj(const float* __restrict__ x,
                                                const short* __restrict__ Wt,
                                                short* __restrict__ Qo,
                                                short* __restrict__ Ko,
                                                short* __restrict__ Vo) {
  __shared__ char lds_raw[8192 + 24576];
  char* xsb = lds_raw;
  char* wtb = lds_raw + 8192;
  const int tid = threadIdx.x;
  const int lane = tid & 63;
  const int wave = tid >> 6;
  const int l15 = lane & 15;
  const int hi = lane >> 4;
  const int m0 = blockIdx.x * 32;
  const int mr = (wave & 1) * 16;        // wave's row group
  const int ncol = (wave >> 1) * 96;     // wave's col group (6 frags)

  f32x4 acc[6];
#pragma unroll
  for (int f = 0; f < 6; ++f) acc[f] = (f32x4){0.f, 0.f, 0.f, 0.f};

  for (int k0 = 0; k0 < NC; k0 += 64) {
    __syncthreads();
    // stage x: 8192 B, 2 issues/wave
#pragma unroll
    for (int i = 0; i < 2; ++i) {
      int off = wave * 2048 + i * 1024 + lane * 16;
      int ol = off ^ (((off >> 8) & 7) << 4);
      int row = ol >> 8, col = (ol >> 2) & 63;
      gload_lds16(x + (size_t)(m0 + row) * NC + k0 + col, xsb + wave * 2048 + i * 1024);
    }
    // stage Wt: 24576 B, 6 issues/wave
#pragma unroll
    for (int i = 0; i < 6; ++i) {
      int off = wave * 6144 + i * 1024 + lane * 16;
      int ol = off ^ (((off >> 7) & 7) << 4);
      int row = ol >> 7, col = (ol >> 1) & 63;
      gload_lds16(Wt + (size_t)row * NC + k0 + col, wtb + wave * 6144 + i * 1024);
    }
    __syncthreads();
#pragma unroll
    for (int s = 0; s < 2; ++s) {
      // a-frag: x row mr+l15, k = s*32 + hi*8 (fp32 -> bf16)
      int r = mr + l15;
      int o1 = (r * 256 + s * 128 + hi * 32) ^ ((r & 7) << 4);
      int o2 = (r * 256 + s * 128 + hi * 32 + 16) ^ ((r & 7) << 4);
      float4 q0 = *(const float4*)(xsb + o1);
      float4 q1 = *(const float4*)(xsb + o2);
      bf16x8 a;
      a[0] = f2bf(q0.x); a[1] = f2bf(q0.y); a[2] = f2bf(q0.z); a[3] = f2bf(q0.w);
      a[4] = f2bf(q1.x); a[5] = f2bf(q1.y); a[6] = f2bf(q1.z); a[7] = f2bf(q1.w);
#pragma unroll
      for (int f = 0; f < 6; ++f) {
        int c = ncol + f * 16 + l15;
        int ob = (c * 128 + s * 64 + hi * 16) ^ ((c & 7) << 4);
        bf16x8 b = *(const bf16x8*)(wtb + ob);
        acc[f] = MFMA(a, b, acc[f]);
      }
    }
  }
  // epilogue
#pragma unroll
  for (int f = 0; f < 6; ++f) {
    int g = ncol + f * 16 + l15;          // global col 0..191
    int mat = g >> 6, h = g & 63;
    short* dst = (mat == 0) ? Qo : (mat == 1) ? Ko : Vo;
#pragma unroll
    for (int r = 0; r < 4; ++r) {
      int t = m0 + mr + hi * 4 + r;
      dst[(size_t)t * NH + h] = f2bf(acc[f][r]);
    }
  }
}

// ---------------------------------------------------------------------------
// Kernel 2a: flash attention partial (split-K). Grid 8*32*8 = 2048 blocks.
// Block (b, qt, kc): q-rows [qt*64, qt*64+64), key tiles kc*4 .. min(kc*4+3, qt).
// Writes unnormalized O (bf16) + (m, l) per row to ws.
// ---------------------------------------------------------------------------
__global__ __launch_bounds__(256) void attn_partial(const short* __restrict__ Q,
                                                    const short* __restrict__ K,
                                                    const short* __restrict__ V,
                                                    short* __restrict__ Op,
                                                    float2* __restrict__ ml) {
  const int bid = blockIdx.x;
  const int b = bid >> 8;
  const int qt = (bid >> 3) & 31;
  const int kc = bid & 7;
  if (kc * 4 > qt) return;
  const int kt0 = kc * 4;
  const int kte = min(kt0 + 4, qt + 1);

  __shared__ short Ks[64][72];
  __shared__ short Vt[64][72];
  __shared__ short Ps[4][16][72];
  const int tid = threadIdx.x;
  const int lane = tid & 63;
  const int wave = tid >> 6;
  const int l15 = lane & 15;
  const int hi = lane >> 4;
  const int kgrp = hi * 8;

  const size_t qoff = ((size_t)b * NT + qt * 64) * NH;
  const int qrow = wave * 16 + l15;
  const bf16x8 qf0 = *(const bf16x8*)(Q + qoff + (size_t)qrow * NH + kgrp);
  const bf16x8 qf1 = *(const bf16x8*)(Q + qoff + (size_t)qrow * NH + 32 + kgrp);

  f32x4 oacc[4];
#pragma unroll
  for (int f = 0; f < 4; ++f) oacc[f] = (f32x4){0.f, 0.f, 0.f, 0.f};
  float m_[4], l_[4];
#pragma unroll
  for (int r = 0; r < 4; ++r) { m_[r] = -INFINITY; l_[r] = 0.f; }

  for (int kt = kt0; kt < kte; ++kt) {
    __syncthreads();
    {
      int r = tid >> 2, c0 = (tid & 3) * 16;
      const size_t base = ((size_t)b * NT + kt * 64 + r) * NH + c0;
      bf16x8 k0 = *(const bf16x8*)(K + base);
      bf16x8 k1 = *(const bf16x8*)(K + base + 8);
      *(bf16x8*)&Ks[r][c0] = k0;
      *(bf16x8*)&Ks[r][c0 + 8] = k1;
      bf16x8 v0 = *(const bf16x8*)(V + base);
      bf16x8 v1 = *(const bf16x8*)(V + base + 8);
#pragma unroll
      for (int i = 0; i < 8; ++i) Vt[c0 + i][r] = v0[i];
#pragma unroll
      for (int i = 0; i < 8; ++i) Vt[c0 + 8 + i][r] = v1[i];
    }
    __syncthreads();

    f32x4 s[4];
#pragma unroll
    for (int f = 0; f < 4; ++f) {
      s[f] = (f32x4){0.f, 0.f, 0.f, 0.f};
      bf16x8 b0 = *(const bf16x8*)&Ks[f * 16 + l15][kgrp];
      bf16x8 b1 = *(const bf16x8*)&Ks[f * 16 + l15][32 + kgrp];
      s[f] = MFMA(qf0, b0, s[f]);
      s[f] = MFMA(qf1, b1, s[f]);
    }
    if (kt == qt) {
#pragma unroll
      for (int f = 0; f < 4; ++f)
#pragma unroll
        for (int r = 0; r < 4; ++r)
          if (f * 16 + l15 > wave * 16 + hi * 4 + r) s[f][r] = -INFINITY;
    }
    float mt[4];
#pragma unroll
    for (int r = 0; r < 4; ++r)
      mt[r] = fmaxf(fmaxf(s[0][r], s[1][r]), fmaxf(s[2][r], s[3][r]));
#pragma unroll
    for (int d = 1; d < 16; d <<= 1)
#pragma unroll
      for (int r = 0; r < 4; ++r) mt[r] = fmaxf(mt[r], __shfl_xor(mt[r], d));
    float alpha[4], rs[4];
#pragma unroll
    for (int r = 0; r < 4; ++r) {
      float mn = fmaxf(m_[r], mt[r]);
      alpha[r] = __expf(m_[r] - mn);
      m_[r] = mn;
      rs[r] = 0.f;
    }
#pragma unroll
    for (int f = 0; f < 4; ++f)
#pragma unroll
      for (int r = 0; r < 4; ++r) {
        float p = __expf(s[f][r] - m_[r]);
        s[f][r] = p;
        rs[r] += p;
      }
#pragma unroll
    for (int d = 1; d < 16; d <<= 1)
#pragma unroll
      for (int r = 0; r < 4; ++r) rs[r] += __shfl_xor(rs[r], d);
#pragma unroll
    for (int r = 0; r < 4; ++r) l_[r] = l_[r] * alpha[r] + rs[r];
#pragma unroll
    for (int f = 0; f < 4; ++f)
#pragma unroll
      for (int r = 0; r < 4; ++r) oacc[f][r] *= alpha[r];

#pragma unroll
    for (int f = 0; f < 4; ++f)
#pragma unroll
      for (int r = 0; r < 4; ++r)
        Ps[wave][hi * 4 + r][f * 16 + l15] = f2bf(s[f][r]);

    bf16x8 pa0 = *(const bf16x8*)&Ps[wave][l15][kgrp];
    bf16x8 pa1 = *(const bf16x8*)&Ps[wave][l15][32 + kgrp];
#pragma unroll
    for (int f = 0; f < 4; ++f) {
      bf16x8 vb0 = *(const bf16x8*)&Vt[f * 16 + l15][kgrp];
      bf16x8 vb1 = *(const bf16x8*)&Vt[f * 16 + l15][32 + kgrp];
      oacc[f] = MFMA(pa0, vb0, oacc[f]);
      oacc[f] = MFMA(pa1, vb1, oacc[f]);
    }
  }
  // epilogue: unnormalized partial O (bf16) + per-row (m, l)
  short* op = Op + ((size_t)bid << 12);
#pragma unroll
  for (int f = 0; f < 4; ++f)
#pragma unroll
    for (int r = 0; r < 4; ++r)
      op[(wave * 16 + hi * 4 + r) * 64 + f * 16 + l15] = f2bf(oacc[f][r]);
  if (l15 == 0) {
#pragma unroll
    for (int r = 0; r < 4; ++r) {
      int row = wave * 16 + hi * 4 + r;
      ml[(size_t)bid * 64 + row] = make_float2(m_[r], l_[r]);
    }
  }
}

// ---------------------------------------------------------------------------
// Kernel 2b: combine partials. Grid 256 blocks (b, qt), 256 threads.
// thread: row r = tid>>2, h-chunk h0 = (tid&3)*16.
// ---------------------------------------------------------------------------
__global__ __launch_bounds__(256) void attn_combine(const short* __restrict__ Op,
                                                    const float2* __restrict__ ml,
                                                    float* __restrict__ out) {
  const int bid = blockIdx.x;
  const int b = bid >> 5;
  const int qt = bid & 31;
  const int nch = (qt >> 2) + 1;
  const int tid = threadIdx.x;
  const int r = tid >> 2;
  const int h0 = (tid & 3) * 16;
  const int slot0 = bid * 8;   // == (b*32+qt)*8

  float M = -INFINITY;
#pragma unroll 8
  for (int i = 0; i < 8; ++i)
    if (i < nch) M = fmaxf(M, ml[(size_t)(slot0 + i) * 64 + r].x);

  float L = 0.f;
  float o[16];
#pragma unroll
  for (int j = 0; j < 16; ++j) o[j] = 0.f;
#pragma unroll 8
  for (int i = 0; i < 8; ++i) {
    if (i < nch) {
      float2 t = ml[(size_t)(slot0 + i) * 64 + r];
      float w = __expf(t.x - M);
      L += w * t.y;
      const short* p = Op + (((size_t)(slot0 + i)) << 12) + r * 64 + h0;
      bf16x8 v0 = *(const bf16x8*)p;
      bf16x8 v1 = *(const bf16x8*)(p + 8);
#pragma unroll
      for (int j = 0; j < 8; ++j) {
        o[j] += w * bf2f(v0[j]);
        o[8 + j] += w * bf2f(v1[j]);
      }
    }
  }
  float inv = 1.f / L;
  float* po = out + (((size_t)b * NT) + qt * 64 + r) * NH + h0;
#pragma unroll
  for (int j = 0; j < 4; ++j) {
    float4 v = {o[j * 4] * inv, o[j * 4 + 1] * inv, o[j * 4 + 2] * inv, o[j * 4 + 3] * inv};
    *(float4*)(po + j * 4) = v;
  }
}

// ---------------------------------------------------------------------------
// Kernel 2 (fallback if ws too small): monolithic flash attention (round 1).
// ---------------------------------------------------------------------------
__global__ __launch_bounds__(256) void attn(const short* __restrict__ Q,
                                            const short* __restrict__ K,
                                            const short* __restrict__ V,
                                            float* __restrict__ out) {
  __shared__ short Ks[64][72];
  __shared__ short Vt[64][72];
  __shared__ short Ps[4][16][72];
  const int tid = threadIdx.x;
  const int lane = tid & 63;
  const int wave = tid >> 6;
  const int l15 = lane & 15;
  const int hi = lane >> 4;
  const int kgrp = hi * 8;
  const int b = blockIdx.x >> 5;
  const int qt = blockIdx.x & 31;

  const size_t qoff = ((size_t)b * NT + qt * 64) * NH;
  const int qrow = wave * 16 + l15;
  const bf16x8 qf0 = *(const bf16x8*)(Q + qoff + (size_t)qrow * NH + kgrp);
  const bf16x8 qf1 = *(const bf16x8*)(Q + qoff + (size_t)qrow * NH + 32 + kgrp);

  f32x4 oacc[4];
#pragma unroll
  for (int f = 0; f < 4; ++f) oacc[f] = (f32x4){0.f, 0.f, 0.f, 0.f};
  float m_[4], l_[4];
#pragma unroll
  for (int r = 0; r < 4; ++r) { m_[r] = -INFINITY; l_[r] = 0.f; }

  for (int kt = 0; kt <= qt; ++kt) {
    __syncthreads();
    {
      int r = tid >> 2, c0 = (tid & 3) * 16;
      const size_t base = ((size_t)b * NT + kt * 64 + r) * NH + c0;
      bf16x8 k0 = *(const bf16x8*)(K + base);
      bf16x8 k1 = *(const bf16x8*)(K + base + 8);
      *(bf16x8*)&Ks[r][c0] = k0;
      *(bf16x8*)&Ks[r][c0 + 8] = k1;
      bf16x8 v0 = *(const bf16x8*)(V + base);
      bf16x8 v1 = *(const bf16x8*)(V + base + 8);
#pragma unroll
      for (int i = 0; i < 8; ++i) Vt[c0 + i][r] = v0[i];
#pragma unroll
      for (int i = 0; i < 8; ++i) Vt[c0 + 8 + i][r] = v1[i];
    }
    __syncthreads();

    f32x4 s[4];
#pragma unroll
    for (int f = 0; f < 4; ++f) {
      s[f] = (f32x4){0.f, 0.f, 0.f, 0.f};
      bf16x8 b0 = *(const bf16x8*)&Ks[f * 16 + l15][kgrp];
      bf16x8 b1 = *(const bf16x8*)&Ks[f * 16 + l15][32 + kgrp];
      s[f] = MFMA(qf0, b0, s[f]);
      s[f] = MFMA(qf1, b1, s[f]);
    }
    if (kt == qt) {
#pragma unroll
      for (int f = 0; f < 4; ++f)
#pragma unroll
        for (int r = 0; r < 4; ++r)
          if (f * 16 + l15 > wave * 16 + hi * 4 + r) s[f][r] = -INFINITY;
    }
    float mt[4];
#pragma unroll
    for (int r = 0; r < 4; ++r)
      mt[r] = fmaxf(fmaxf(s[0][r], s[1][r]), fmaxf(s[2][r], s[3][r]));
#pragma unroll
    for (int d = 1; d < 16; d <<= 1)
#pragma unroll
      for (int r = 0; r < 4; ++r) mt[r] = fmaxf(mt[r], __shfl_xor(mt[r], d));
    float alpha[4], rs[4];
#pragma unroll
    for (int r = 0; r < 4; ++r) {
      float mn = fmaxf(m_[r], mt[r]);
      alpha[r] = __expf(m_[r] - mn);
      m_[r] = mn;
      rs[r] = 0.f;
    }
#pragma unroll
    for (int f = 0; f < 4; ++f)
#pragma unroll
      for (int r = 0; r < 4; ++r) {
        float p = __expf(s[f][r] - m_[r]);
        s[f][r] = p;
        rs[r] += p;
      }
#pragma unroll
    for (int d = 1; d < 16; d <<= 1)
#pragma unroll
      for (int r = 0; r < 4; ++r) rs[r] += __shfl_xor(rs[r], d);
#pragma unroll
    for (int r = 0; r < 4; ++r) l_[r] = l_[r] * alpha[r] + rs[r];
#pragma unroll
    for (int f = 0; f < 4; ++f)
#pragma unroll
      for (int r = 0; r < 4; ++r) oacc[f][r] *= alpha[r];

#pragma unroll
    for (int f = 0; f < 4; ++f)
#pragma unroll
      for (int r = 0; r < 4; ++r)
        Ps[wave][hi * 4 + r][f * 16 + l15] = f2bf(s[f][r]);

    bf16x8 pa0 = *(const bf16x8*)&Ps[wave][l15][kgrp];
    bf16x8 pa1 = *(const bf16x8*)&Ps[wave][l15][32 + kgrp];
#pragma unroll
    for (int f = 0; f < 4; ++f) {
      bf16x8 vb0 = *(const bf16x8*)&Vt[f * 16 + l15][kgrp];
      bf16x8 vb1 = *(const bf16x8*)&Vt[f * 16 + l15][32 + kgrp];
      oacc[f] = MFMA(pa0, vb0, oacc[f]);
      oacc[f] = MFMA(pa1, vb1, oacc[f]);
    }
  }
#pragma unroll
  for (int f = 0; f < 4; ++f)
#pragma unroll
    for (int r = 0; r < 4; ++r) {
      int t = qt * 64 + wave * 16 + hi * 4 + r;
      out[((size_t)b * NT + t) * NH + f * 16 + l15] = oacc[f][r] / l_[r];
    }
}

// ---------------------------------------------------------------------------
extern "C" void kernel_launch(void* const* d_in, const int* in_sizes, int n_in,
                              void* d_out, int out_size, void* d_ws, size_t ws_size,
                              hipStream_t stream) {
  const float* x  = (const float*)d_in[0];
  const float* Wq = (const float*)d_in[1];
  const float* Wk = (const float*)d_in[2];
  const float* Wv = (const float*)d_in[3];
  float* out = (float*)d_out;

  char* ws = (char*)d_ws;
  short* Wt = (short*)ws;                          // 384 KB
  short* Qb = (short*)(ws + (size_t)(1 << 20));
  short* Kb = (short*)(ws + (size_t)(3 << 20));
  short* Vb = (short*)(ws + (size_t)(5 << 20));
  short* Op = (short*)(ws + (size_t)(8 << 20));        // 16 MB (2048 x 4096 bf16)
  float2* ml = (float2*)(ws + (size_t)25165824);       // 1 MB
  const size_t need = 26214400;

  hipLaunchKernelGGL(w_prep, dim3(48), dim3(256), 0, stream, Wq, Wk, Wv, Wt);
  hipLaunchKernelGGL(qkv_proj, dim3(512), dim3(256), 0, stream, x, Wt, Qb, Kb, Vb);
  if (ws_size >= need) {
    hipLaunchKernelGGL(attn_partial, dim3(2048), dim3(256), 0, stream, Qb, Kb, Vb, Op, ml);
    hipLaunchKernelGGL(attn_combine, dim3(256), dim3(256), 0, stream, Op, ml, out);
  } else {
    hipLaunchKernelGGL(attn, dim3(8 * 32), dim3(256), 0, stream, Qb, Kb, Vb, out);
  }
}